// Round 4
// baseline (197.927 us; speedup 1.0000x reference)
//
#include <hip/hip_runtime.h>

// SimpleGraphSAGE on MI355X — round 15.
// dst = repeat(arange(N),16) -> node i's edges are src[16i..16i+16), deg==16.
//
// History: R12 4-lane dwordx4 gather 49us/layer; R13 batched load window
// REGRESSED (L2 pressure); R14 vectorized self staging 42us/layer, 164.4us.
// Lane-address model: ~1-2 cyc per VMEM lane-address; addresses now trimmed.
// R15: the matmul phase is 2048 scalar FMAs = 4096 VALU-issue cyc/wave
// (~10us/CU/layer). Replace with MFMA v_mfma_f32_16x16x16f16 (32/wave):
// A-frags (fp16) staged straight into swizzled chunk-linear LDS by the
// staging+gather phases; W pre-converted to fp16 frag tables (prep_w);
// D de-transposed via LDS back to the old per-node epilogue.
// fp16 everywhere (2^-11): neighbor half already fp8-quantized, self/W
// rounding negligible, and the h inter-layer table upgrades bf16->fp16,
// so absmax should not grow (may shrink).

#define NN   100000
#define DEG  16
#define F    64
#define NPB  64           // nodes per block (256 threads, 4 waves)
#define STR  65           // LDS column stride for fallback kernel
#define JPW  16           // output columns per wave
#define EDG  (NN * DEG)
#define OSTR 68           // out-transpose LDS stride (16B aligned, 2-way banks)

#if __has_builtin(__builtin_amdgcn_cvt_pk_f32_fp8) && __has_builtin(__builtin_amdgcn_cvt_pk_fp8_f32)
#define HW_FP8 1
#else
#define HW_FP8 0
#endif

typedef float v2f __attribute__((ext_vector_type(2)));
typedef _Float16 f16x4 __attribute__((ext_vector_type(4)));
typedef _Float16 f16x8 __attribute__((ext_vector_type(8)));
typedef float f32x4 __attribute__((ext_vector_type(4)));

// ---- fp8 e4m3 helpers (HW path on gfx950; manual RNE fallback) ----
#if !HW_FP8
__device__ __forceinline__ unsigned fp8_enc1(float f) {  // e4m3fn RNE, saturating
    const unsigned u = __float_as_uint(f);
    const unsigned s = (u >> 31) << 7;
    const float af = fabsf(f);
    if (!(af < 448.f)) return s | 0x7E;                  // sat (also NaN->max)
    if (af < 0.015625f) {                                // subnormal, step 2^-9
        const int n = (int)rintf(af * 512.f);            // 0..8 (8 -> min normal)
        return s | (unsigned)n;
    }
    unsigned au = u & 0x7FFFFFFFu;
    const unsigned lsb = (au >> 20) & 1u;
    au += 0x7FFFFu + lsb;                                // RNE at bit 20
    const int e = (int)(au >> 23) - 127;
    if (e > 8) return s | 0x7E;
    return s | ((unsigned)(e + 7) << 3) | ((au >> 20) & 7u);
}
__device__ __forceinline__ float fp8_dec1(unsigned c) {
    const unsigned s = c >> 7;
    const int e = (int)((c >> 3) & 15u);
    const unsigned m = c & 7u;
    const float v = e ? ldexpf((float)(8 + m), e - 10) : ldexpf((float)m, -9);
    return s ? -v : v;
}
#endif

__device__ __forceinline__ unsigned fp8_pack4(float a, float b, float c, float d) {
#if HW_FP8
    int t = __builtin_amdgcn_cvt_pk_fp8_f32(a, b, 0, false);
    t     = __builtin_amdgcn_cvt_pk_fp8_f32(c, d, t, true);
    return (unsigned)t;
#else
    return fp8_enc1(a) | (fp8_enc1(b) << 8) | (fp8_enc1(c) << 16) | (fp8_enc1(d) << 24);
#endif
}

__device__ __forceinline__ void fp8_acc4(unsigned d, float* acc) {
#if HW_FP8
    const v2f lo = __builtin_amdgcn_cvt_pk_f32_fp8((int)d, false);
    const v2f hi = __builtin_amdgcn_cvt_pk_f32_fp8((int)d, true);
    acc[0] += lo.x; acc[1] += lo.y; acc[2] += hi.x; acc[3] += hi.y;
#else
    acc[0] += fp8_dec1(d & 0xffu);
    acc[1] += fp8_dec1((d >> 8) & 0xffu);
    acc[2] += fp8_dec1((d >> 16) & 0xffu);
    acc[3] += fp8_dec1(d >> 24);
#endif
}

// x (fp32) -> fp8 gather table
__global__ __launch_bounds__(256)
void cvt_f32_fp8(const float* __restrict__ in, unsigned* __restrict__ out, int n4)
{
    int i = blockIdx.x * 256 + threadIdx.x;
    if (i < n4) {
        float4 v = ((const float4*)in)[i];
        out[i] = fp8_pack4(v.x, v.y, v.z, v.w);
    }
}

// W (fp32 [2F,F]) -> fp16 B-fragment tables for v_mfma_f32_16x16x16f16.
// B-frag: col = nt*16 + (l&15), k = kt*16 + (l>>4)*4 + j.
// Layout: Wh[layer][((nt*8 + kt)*64 + l)*4 + j], 8192 halves (16 KB) per layer.
__global__ __launch_bounds__(256)
void prep_w(const float* __restrict__ W1, const float* __restrict__ W2,
            _Float16* __restrict__ Wh)
{
    const int idx = blockIdx.x * 256 + threadIdx.x;   // 0..4095 chunks
    if (idx >= 4096) return;
    const float* Wsrc = (idx >= 2048) ? W2 : W1;
    const int rem = idx & 2047;
    const int nt = rem >> 9, kt = (rem >> 6) & 7, l = rem & 63;
    const int col = nt * 16 + (l & 15);
    const int k0  = kt * 16 + (l >> 4) * 4;
    f16x4 h;
    #pragma unroll
    for (int j = 0; j < 4; ++j)
        h[j] = (_Float16)Wsrc[(size_t)(k0 + j) * F + col];
    *(f16x4*)(Wh + (size_t)idx * 4) = h;
}

// Batcher odd-even mergesort, 16 keys, fully unrolled -> registers only.
__device__ __forceinline__ void ce(unsigned& a, unsigned& b) {
    const unsigned lo = min(a, b), hi = max(a, b); a = lo; b = hi;
}
__device__ __forceinline__ void sort16(unsigned s[16]) {
    #pragma unroll
    for (int p = 1; p < 16; p <<= 1) {
        #pragma unroll
        for (int k = p; k >= 1; k >>= 1) {
            #pragma unroll
            for (int j = k & (p - 1); j + k < 16; j += 2 * k) {
                #pragma unroll
                for (int i = 0; i < k; ++i) {
                    if (i + j + k < 16)
                        if ((i + j) / (2 * p) == (i + j + k) / (2 * p))
                            ce(s[i + j], s[i + j + k]);
                }
            }
        }
    }
}

// A-fragment chunk index (8B chunks). Logical: element k = kt*16 + sub*4 + j
// of node row (mt*16 + r). sub innermost so (sub,sub+1) pairs are 16B-contig.
// XOR-swizzle kt into the r-low bits to spread write banks.
__device__ __forceinline__ int aChunk(int mt, int kt, int r, int sub) {
    return (((((mt * 8 + kt) * 16 + r) << 2) | sub)) ^ ((kt & 3) << 2);
}

// ---------------- fused layer: sorted fp8 gather + MFMA matmul ----------------
template<bool RELU, bool SELF_F32, bool EMIT_F32>
__global__ __launch_bounds__(256, 4)
void sage_fused(const float*  __restrict__ selfA,      // [NN,F] fp32 (if SELF_F32)
                const ushort* __restrict__ selfH,      // [NN,F] fp16 (else)
                const unsigned char* __restrict__ gat, // [NN,F] fp8 table
                const _Float16* __restrict__ Wf,       // fp16 B-frag table
                const float*  __restrict__ bias,       // [F]
                const int*    __restrict__ src,        // [EDG]
                float*        __restrict__ out_f32,    // if EMIT_F32
                ushort*       __restrict__ out_h16,    // else: h table (self, fp16)
                unsigned char* __restrict__ out_fp8)   // else: h table (gather)
{
    // phase 1: A-frag staging area (16 KB); phase 2: out transpose (17.4 KB)
    __shared__ __align__(16) unsigned char smem[NPB * OSTR * 4];

    const int tid   = threadIdx.x;
    const int lane  = tid & 63;
    const int wave  = __builtin_amdgcn_readfirstlane(tid >> 6);
    const int node0 = blockIdx.x * NPB;

    // ---- Self staging -> fp16 A-frags (K 0..63, kt 0..3) ----
    // thread: node = lane, chunk-col c = m*4 + wave (c in 0..7, 8 halves each)
    #pragma unroll
    for (int m = 0; m < 2; ++m) {
        const int c    = m * 4 + wave;       // kt = c>>1, sub pair = (c&1)*2
        const int node = node0 + lane;
        const int kt   = c >> 1, s2 = (c & 1) * 2;
        const int boff = aChunk(lane >> 4, kt, lane & 15, s2) * 8;
        if (SELF_F32) {
            float4 v0 = make_float4(0.f, 0.f, 0.f, 0.f), v1 = v0;
            if (node < NN) {
                const float* p = selfA + (size_t)node * F + c * 8;
                v0 = ((const float4*)p)[0];
                v1 = ((const float4*)p)[1];
            }
            f16x8 h;
            h[0] = (_Float16)v0.x; h[1] = (_Float16)v0.y;
            h[2] = (_Float16)v0.z; h[3] = (_Float16)v0.w;
            h[4] = (_Float16)v1.x; h[5] = (_Float16)v1.y;
            h[6] = (_Float16)v1.z; h[7] = (_Float16)v1.w;
            *(f16x8*)(smem + boff) = h;
        } else {
            uint4 v = make_uint4(0u, 0u, 0u, 0u);
            if (node < NN)
                v = *(const uint4*)(selfH + (size_t)node * F + c * 8);
            *(uint4*)(smem + boff) = v;      // raw fp16 copy, no decode
        }
    }

    // ---- Sorted fp8 gather -> fp16 A-frags (K 64..127, kt 4..7) ----
    // 4-lane group per node; lane q covers features 16q..16q+15 (kt = 4+q).
    {
        const int q     = lane & 3;
        const int g     = lane >> 2;         // node within wave = r
        const int nloc  = wave * JPW + g;
        const int n     = node0 + nloc;
        const bool v    = n < NN;

        unsigned s[DEG];
        {
            const int4* p = (const int4*)(src + (size_t)n * DEG);
            #pragma unroll
            for (int t = 0; t < 4; ++t) {
                const int4 a = v ? p[t] : make_int4(0, 0, 0, 0);
                s[4*t+0] = a.x; s[4*t+1] = a.y;
                s[4*t+2] = a.z; s[4*t+3] = a.w;
            }
        }
        sort16(s);

        float a[16];
        #pragma unroll
        for (int f = 0; f < 16; ++f) a[f] = 0.f;

        #pragma unroll
        for (int e = 0; e < DEG; ++e) {
            // one 16B load per lane; 4 lanes cover the 64B row (1 line)
            const uint4 r = *(const uint4*)(gat + (size_t)s[e] * F + q * 16);
            fp8_acc4(r.x, a);
            fp8_acc4(r.y, a + 4);
            fp8_acc4(r.z, a + 8);
            fp8_acc4(r.w, a + 12);
        }

        const float sc = 1.0f / DEG;
        f16x8 h0, h1;
        #pragma unroll
        for (int t = 0; t < 8; ++t) {
            h0[t] = (_Float16)(a[t]     * sc);
            h1[t] = (_Float16)(a[8 + t] * sc);
        }
        const int kt = 4 + q;
        *(f16x8*)(smem + aChunk(wave, kt, g, 0) * 8) = h0;
        *(f16x8*)(smem + aChunk(wave, kt, g, 2) * 8) = h1;
    }
    __syncthreads();

    // ---- MFMA matmul: wave owns N-tile nt = wave (cols j0..j0+15) ----
    const int j0 = wave * JPW;
    const int lr = lane & 15, lq = lane >> 4;

    f16x4 Wk[8];
    #pragma unroll
    for (int kt = 0; kt < 8; ++kt)
        Wk[kt] = *(const f16x4*)(Wf + ((size_t)(wave * 8 + kt) * 64 + lane) * 4);

    const float bv = bias[j0 + lr];
    f32x4 acc[4];
    #pragma unroll
    for (int mt = 0; mt < 4; ++mt) acc[mt] = (f32x4){bv, bv, bv, bv};

    #pragma unroll
    for (int kt = 0; kt < 8; ++kt) {
        #pragma unroll
        for (int mt = 0; mt < 4; ++mt) {
            const f16x4 af = *(const f16x4*)(smem + aChunk(mt, kt, lr, lq) * 8);
            acc[mt] = __builtin_amdgcn_mfma_f32_16x16x16f16(af, Wk[kt], acc[mt], 0, 0, 0);
        }
    }
    __syncthreads();                         // all frag reads done; reuse smem

    // ---- De-transpose D via LDS: D elem (row = mt*16+lq*4+p, col = j0+lr) ----
    float* outS = (float*)smem;
    #pragma unroll
    for (int mt = 0; mt < 4; ++mt)
        #pragma unroll
        for (int p = 0; p < 4; ++p)
            outS[(mt * 16 + lq * 4 + p) * OSTR + j0 + lr] = acc[mt][p];
    // readers are the same wave that wrote (wave w wrote cols j0..j0+15 for
    // all rows) -> lgkmcnt ordering suffices, no barrier.

    float r[JPW];
    #pragma unroll
    for (int t = 0; t < 4; ++t) {
        const float4 v = *(const float4*)(outS + lane * OSTR + j0 + 4 * t);
        r[4*t+0] = v.x; r[4*t+1] = v.y; r[4*t+2] = v.z; r[4*t+3] = v.w;
    }

    const int node = node0 + lane;
    if (node < NN) {
        if (RELU) {
            #pragma unroll
            for (int j = 0; j < JPW; ++j) r[j] = fmaxf(r[j], 0.f);
        }
        if (EMIT_F32) {
            float4* op = (float4*)(out_f32 + (size_t)node * F + j0);
            #pragma unroll
            for (int t = 0; t < 4; ++t)
                op[t] = make_float4(r[4 * t], r[4 * t + 1],
                                    r[4 * t + 2], r[4 * t + 3]);
        } else {
            // h tables: fp16 (self path of layer 2) + fp8 (gather table)
            f16x8 h0, h1;
            #pragma unroll
            for (int t = 0; t < 8; ++t) {
                h0[t] = (_Float16)r[t];
                h1[t] = (_Float16)r[8 + t];
            }
            *(f16x8*)(out_h16 + (size_t)node * F + j0)     = h0;
            *(f16x8*)(out_h16 + (size_t)node * F + j0 + 8) = h1;

            uint4 p;
            #pragma unroll
            for (int t = 0; t < 4; ++t)
                (&p.x)[t] = fp8_pack4(r[4*t], r[4*t+1], r[4*t+2], r[4*t+3]);
            *(uint4*)(out_fp8 + (size_t)node * F + j0) = p;
        }
    }
}

// ---------------- fallback (round-3, all-fp32, fused) ----------------
template<bool RELU>
__global__ __launch_bounds__(256, 4)
void sage_layer_f32(const float* __restrict__ feat,
                    const float* __restrict__ W,
                    const float* __restrict__ bias,
                    const int*   __restrict__ src,
                    float*       __restrict__ out)
{
    __shared__ float buf[2 * F][STR];
    const int tid   = threadIdx.x;
    const int lane  = tid & 63;
    const int wave  = __builtin_amdgcn_readfirstlane(tid >> 6);
    const int node0 = blockIdx.x * NPB;

    #pragma unroll 2
    for (int m = 0; m < NPB / 4; ++m) {
        const int n    = wave * (NPB / 4) + m;
        const int node = node0 + n;
        if (node < NN) {
            buf[lane][n] = feat[node * F + lane];
            const int* sp = src + node * DEG;
            float s = 0.f;
            #pragma unroll
            for (int e = 0; e < DEG; ++e) s += feat[sp[e] * F + lane];
            buf[F + lane][n] = s * (1.0f / DEG);
        }
    }
    __syncthreads();

    const int j0 = wave * JPW;
    float acc[JPW];
    #pragma unroll
    for (int j = 0; j < JPW; ++j) acc[j] = bias[j0 + j];
    #pragma unroll 4
    for (int k = 0; k < 2 * F; ++k) {
        const float v = buf[k][lane];
        const float* Wr = W + k * F + j0;
        #pragma unroll
        for (int j = 0; j < JPW; ++j) acc[j] = fmaf(v, Wr[j], acc[j]);
    }
    const int node = node0 + lane;
    if (node < NN) {
        float4* op = (float4*)(out + node * F + j0);
        #pragma unroll
        for (int t = 0; t < 4; ++t) {
            float4 r = make_float4(acc[4 * t], acc[4 * t + 1],
                                   acc[4 * t + 2], acc[4 * t + 3]);
            if (RELU) {
                r.x = fmaxf(r.x, 0.f); r.y = fmaxf(r.y, 0.f);
                r.z = fmaxf(r.z, 0.f); r.w = fmaxf(r.w, 0.f);
            }
            op[t] = r;
        }
    }
}

extern "C" void kernel_launch(void* const* d_in, const int* in_sizes, int n_in,
                              void* d_out, int out_size, void* d_ws, size_t ws_size,
                              hipStream_t stream) {
    const float* x   = (const float*)d_in[0];
    const float* W1  = (const float*)d_in[1];
    const float* b1  = (const float*)d_in[2];
    const float* W2  = (const float*)d_in[3];
    const float* b2  = (const float*)d_in[4];
    const int*   src = (const int*)d_in[5];

    float* out = (float*)d_out;
    const int blocks = (NN + NPB - 1) / NPB;   // 1563

    const size_t hFP8 = (size_t)NN * F;                   //  6.4 MB
    const size_t hF16 = (size_t)NN * F * sizeof(ushort);  // 12.8 MB
    const size_t wTab = 2 * 8192 * sizeof(ushort);        // 32 KB fp16 W frags

    if (ws_size >= 2 * hFP8 + hF16 + wTab) {
        unsigned char* x_fp8 = (unsigned char*)d_ws;
        ushort*        h_16  = (ushort*)((char*)d_ws + hFP8);
        unsigned char* h_fp8 = (unsigned char*)d_ws + hFP8 + hF16;
        _Float16*      Wh    = (_Float16*)((char*)d_ws + 2 * hFP8 + hF16);

        const int n4 = NN * F / 4;
        cvt_f32_fp8<<<(n4 + 255) / 256, 256, 0, stream>>>(x, (unsigned*)x_fp8, n4);
        prep_w<<<16, 256, 0, stream>>>(W1, W2, Wh);
        sage_fused<true,  true,  false><<<blocks, 256, 0, stream>>>(
            x, nullptr, x_fp8, Wh, b1, src, nullptr, h_16, h_fp8);
        sage_fused<false, false, true ><<<blocks, 256, 0, stream>>>(
            nullptr, h_16, h_fp8, Wh + 8192, b2, src, out, nullptr, nullptr);
    } else {
        float* h = (float*)d_ws;
        sage_layer_f32<true ><<<blocks, 256, 0, stream>>>(x, W1, b1, src, h);
        sage_layer_f32<false><<<blocks, 256, 0, stream>>>(h, W2, b2, src, out);
    }
}

// Round 5
// 159.414 us; speedup vs baseline: 1.2416x; 1.2416x over previous
//
#include <hip/hip_runtime.h>

// SimpleGraphSAGE on MI355X — round 16.
// dst = repeat(arange(N),16) -> node i's edges are src[16i..16i+16), deg==16.
//
// History: R12 4-lane dwordx4 gather 49us/layer; R13 deep load window
// REGRESSED (L2 pressure); R14 vectorized self staging 42us/layer, 164.4us;
// R15 MFMA restructure REGRESSED (58us/layer: strided self staging re-fetched
// x ~3x, 2.6M LDS conflicts, FETCH 104MB) -> fully reverted to R14 structure.
// Measured split of 42us/layer: ~28us gather row machinery (latency/TA),
// ~15us VALU (matmul 2048 FMA = 4096 issue cyc/wave), partial overlap.
// R16 (surgical, gather untouched):
//  (a) bufA fp32 -> packed fp16 pairs: LDS 25KB -> 16.6KB -> 8 blocks/CU
//      (+33% waves for gather latency hiding). h table bf16 -> fp16 (the
//      bf16 ulp of h in [2,4) was exactly the 2^-7 absmax term -> shrinks).
//  (b) float2 accumulators + elementwise_fma -> v_pk_fma_f32, halving
//      matmul VALU issue; packed LDS also halves ds_read count.

#define NN   100000
#define DEG  16
#define F    64
#define NPB  64           // nodes per block (256 threads, 4 waves)
#define STR  65           // LDS column stride (+1 pad)
#define JPW  16           // output columns per wave
#define EDG  (NN * DEG)

#if __has_builtin(__builtin_amdgcn_cvt_pk_f32_fp8) && __has_builtin(__builtin_amdgcn_cvt_pk_fp8_f32)
#define HW_FP8 1
#else
#define HW_FP8 0
#endif

typedef float v2f  __attribute__((ext_vector_type(2)));
typedef float f32x2 __attribute__((ext_vector_type(2)));

// ---- fp16 pack/unpack (RNE via _Float16 casts) ----
__device__ __forceinline__ unsigned pkh(float a, float b) {
    union { _Float16 h[2]; unsigned u; } t;
    t.h[0] = (_Float16)a; t.h[1] = (_Float16)b;
    return t.u;
}
__device__ __forceinline__ float h_lo(unsigned d) {
    union { unsigned u; _Float16 h[2]; } t; t.u = d; return (float)t.h[0];
}
__device__ __forceinline__ float h_hi(unsigned d) {
    union { unsigned u; _Float16 h[2]; } t; t.u = d; return (float)t.h[1];
}

// ---- fp8 e4m3 helpers (HW path on gfx950; manual RNE fallback) ----
#if !HW_FP8
__device__ __forceinline__ unsigned fp8_enc1(float f) {  // e4m3fn RNE, saturating
    const unsigned u = __float_as_uint(f);
    const unsigned s = (u >> 31) << 7;
    const float af = fabsf(f);
    if (!(af < 448.f)) return s | 0x7E;                  // sat (also NaN->max)
    if (af < 0.015625f) {                                // subnormal, step 2^-9
        const int n = (int)rintf(af * 512.f);            // 0..8 (8 -> min normal)
        return s | (unsigned)n;
    }
    unsigned au = u & 0x7FFFFFFFu;
    const unsigned lsb = (au >> 20) & 1u;
    au += 0x7FFFFu + lsb;                                // RNE at bit 20
    const int e = (int)(au >> 23) - 127;
    if (e > 8) return s | 0x7E;
    return s | ((unsigned)(e + 7) << 3) | ((au >> 20) & 7u);
}
__device__ __forceinline__ float fp8_dec1(unsigned c) {
    const unsigned s = c >> 7;
    const int e = (int)((c >> 3) & 15u);
    const unsigned m = c & 7u;
    const float v = e ? ldexpf((float)(8 + m), e - 10) : ldexpf((float)m, -9);
    return s ? -v : v;
}
#endif

// pack 4 floats -> 4 fp8 bytes in one dword
__device__ __forceinline__ unsigned fp8_pack4(float a, float b, float c, float d) {
#if HW_FP8
    int t = __builtin_amdgcn_cvt_pk_fp8_f32(a, b, 0, false);
    t     = __builtin_amdgcn_cvt_pk_fp8_f32(c, d, t, true);
    return (unsigned)t;
#else
    return fp8_enc1(a) | (fp8_enc1(b) << 8) | (fp8_enc1(c) << 16) | (fp8_enc1(d) << 24);
#endif
}

// accumulate 4 fp8 bytes (one dword) into acc[0..3]
__device__ __forceinline__ void fp8_acc4(unsigned d, float* acc) {
#if HW_FP8
    const v2f lo = __builtin_amdgcn_cvt_pk_f32_fp8((int)d, false);
    const v2f hi = __builtin_amdgcn_cvt_pk_f32_fp8((int)d, true);
    acc[0] += lo.x; acc[1] += lo.y; acc[2] += hi.x; acc[3] += hi.y;
#else
    acc[0] += fp8_dec1(d & 0xffu);
    acc[1] += fp8_dec1((d >> 8) & 0xffu);
    acc[2] += fp8_dec1((d >> 16) & 0xffu);
    acc[3] += fp8_dec1(d >> 24);
#endif
}

// x (fp32) -> fp8 gather table
__global__ __launch_bounds__(256)
void cvt_f32_fp8(const float* __restrict__ in, unsigned* __restrict__ out, int n4)
{
    int i = blockIdx.x * 256 + threadIdx.x;
    if (i < n4) {
        float4 v = ((const float4*)in)[i];
        out[i] = fp8_pack4(v.x, v.y, v.z, v.w);
    }
}

// Batcher odd-even mergesort, 16 keys, fully unrolled -> registers only.
__device__ __forceinline__ void ce(unsigned& a, unsigned& b) {
    const unsigned lo = min(a, b), hi = max(a, b); a = lo; b = hi;
}
__device__ __forceinline__ void sort16(unsigned s[16]) {
    #pragma unroll
    for (int p = 1; p < 16; p <<= 1) {
        #pragma unroll
        for (int k = p; k >= 1; k >>= 1) {
            #pragma unroll
            for (int j = k & (p - 1); j + k < 16; j += 2 * k) {
                #pragma unroll
                for (int i = 0; i < k; ++i) {
                    if (i + j + k < 16)
                        if ((i + j) / (2 * p) == (i + j + k) / (2 * p))
                            ce(s[i + j], s[i + j + k]);
                }
            }
        }
    }
}

// ---------------- fused layer: sorted fp8 gather + packed-fp32 matmul ----------------
// pkA[kk][n]: self features 2kk,2kk+1 as packed fp16 pair.
// pkB[kk][n]: neighbor-mean features 2kk,2kk+1 as packed fp16 pair.
template<bool RELU, bool SELF_F32, bool EMIT_F32>
__global__ __launch_bounds__(256, 4)
void sage_fused(const float*  __restrict__ selfA,      // [NN,F] fp32 (if SELF_F32)
                const ushort* __restrict__ selfH,      // [NN,F] fp16 (else)
                const unsigned char* __restrict__ gat, // [NN,F] fp8 table
                const float*  __restrict__ W,          // [2F,F]
                const float*  __restrict__ bias,       // [F]
                const int*    __restrict__ src,        // [EDG]
                float*        __restrict__ out_f32,    // if EMIT_F32
                ushort*       __restrict__ out_h16,    // else: h table (self, fp16)
                unsigned char* __restrict__ out_fp8)   // else: h table (gather)
{
    __shared__ unsigned pkA[F / 2][STR];     // 8.32 KB
    __shared__ unsigned pkB[F / 2][STR];     // 8.32 KB   (16.64 KB total)

    const int tid   = threadIdx.x;
    const int lane  = tid & 63;
    const int wave  = __builtin_amdgcn_readfirstlane(tid >> 6);
    const int node0 = blockIdx.x * NPB;

    // ---- Self staging, vectorized + packed ----
    if (SELF_F32) {
        // i = m*256 + tid -> node = i>>4, fq = i&15 (float4 within row).
        // ds_write bank = (2fq + c + n) % 32 over a wave -> 2-way, free.
        #pragma unroll
        for (int m = 0; m < 4; ++m) {
            const int i    = m * 256 + tid;
            const int n    = i >> 4;
            const int fq   = i & 15;
            const int node = node0 + n;
            float4 v = make_float4(0.f, 0.f, 0.f, 0.f);
            if (node < NN)
                v = *(const float4*)(selfA + (size_t)node * F + fq * 4);
            pkA[2 * fq    ][n] = pkh(v.x, v.y);
            pkA[2 * fq + 1][n] = pkh(v.z, v.w);
        }
    } else {
        // fp16 h rows are 128B: node = i>>3, oc = i&7 (uint4 = 8 fp16).
        // Raw dword copy, no decode. Bank = (4oc + t + n) % 32 -> 2-way.
        #pragma unroll
        for (int m = 0; m < 2; ++m) {
            const int i    = m * 256 + tid;
            const int n    = i >> 3;
            const int oc   = i & 7;
            const int node = node0 + n;
            uint4 v = make_uint4(0u, 0u, 0u, 0u);
            if (node < NN)
                v = *(const uint4*)(selfH + (size_t)node * F + oc * 8);
            pkA[4 * oc + 0][n] = v.x;
            pkA[4 * oc + 1][n] = v.y;
            pkA[4 * oc + 2][n] = v.z;
            pkA[4 * oc + 3][n] = v.w;
        }
    }

    // ---- Sorted fp8 gather: 4-lane group handles ONE node; dwordx4 rows ----
    // (R12 interleaved form; R13's deep batching and R15's restructure both
    // regressed -> keep exactly this.)
    {
        const int q     = lane & 3;          // features 16q .. 16q+15
        const int g     = lane >> 2;         // node within wave
        const int nloc  = wave * JPW + g;
        const int n     = node0 + nloc;
        const bool v    = n < NN;

        unsigned s[DEG];
        {
            const int4* p = (const int4*)(src + (size_t)n * DEG);
            #pragma unroll
            for (int t = 0; t < 4; ++t) {
                const int4 a = v ? p[t] : make_int4(0, 0, 0, 0);
                s[4*t+0] = a.x; s[4*t+1] = a.y;
                s[4*t+2] = a.z; s[4*t+3] = a.w;
            }
        }
        sort16(s);

        float a[16];
        #pragma unroll
        for (int f = 0; f < 16; ++f) a[f] = 0.f;

        #pragma unroll
        for (int e = 0; e < DEG; ++e) {
            // one 16B load per lane; 4 lanes cover the 64B row (1 line)
            const uint4 r = *(const uint4*)(gat + (size_t)s[e] * F + q * 16);
            fp8_acc4(r.x, a);
            fp8_acc4(r.y, a + 4);
            fp8_acc4(r.z, a + 8);
            fp8_acc4(r.w, a + 12);
        }

        // Mean -> packed fp16 pairs; kk = 8q + t covers features 16q+2t, +1.
        const float sc = 1.0f / DEG;
        #pragma unroll
        for (int t = 0; t < 8; ++t)
            pkB[8 * q + t][nloc] = pkh(a[2*t] * sc, a[2*t+1] * sc);
            // bank = (8q+t+g)%32 -> 2-way, free
    }
    __syncthreads();

    // ---- Matmul: lane = node, wave owns j in [16w,16w+16) ----
    // float2 accumulators -> v_pk_fma_f32 (2 FMA/instr).
    const int j0 = wave * JPW;
    f32x2 acc2[8];
    #pragma unroll
    for (int t = 0; t < 8; ++t)
        acc2[t] = *(const f32x2*)(bias + j0 + 2 * t);     // s_load pair

    // Self half (packed fp16 pairs: features 2kk, 2kk+1)
    #pragma unroll 4
    for (int kk = 0; kk < F / 2; ++kk) {
        const unsigned d = pkA[kk][lane];    // ds_read_b32, 2-way = free
        const float vlo = h_lo(d), vhi = h_hi(d);
        const float* Wl = W + (2 * kk)     * F + j0;      // wave-uniform
        const float* Wh = W + (2 * kk + 1) * F + j0;
        #pragma unroll
        for (int t = 0; t < 8; ++t) {
            acc2[t] = __builtin_elementwise_fma((f32x2){vlo, vlo},
                        *(const f32x2*)(Wl + 2 * t), acc2[t]);
            acc2[t] = __builtin_elementwise_fma((f32x2){vhi, vhi},
                        *(const f32x2*)(Wh + 2 * t), acc2[t]);
        }
    }
    // Neighbor half (packed fp16 pairs)
    #pragma unroll 4
    for (int kk = 0; kk < F / 2; ++kk) {
        const unsigned d = pkB[kk][lane];
        const float vlo = h_lo(d), vhi = h_hi(d);
        const float* Wl = W + (F + 2 * kk)     * F + j0;
        const float* Wh = W + (F + 2 * kk + 1) * F + j0;
        #pragma unroll
        for (int t = 0; t < 8; ++t) {
            acc2[t] = __builtin_elementwise_fma((f32x2){vlo, vlo},
                        *(const f32x2*)(Wl + 2 * t), acc2[t]);
            acc2[t] = __builtin_elementwise_fma((f32x2){vhi, vhi},
                        *(const f32x2*)(Wh + 2 * t), acc2[t]);
        }
    }

    const int node = node0 + lane;
    if (node < NN) {
        float r[JPW];
        #pragma unroll
        for (int t = 0; t < 8; ++t) {
            r[2*t]   = RELU ? fmaxf(acc2[t][0], 0.f) : acc2[t][0];
            r[2*t+1] = RELU ? fmaxf(acc2[t][1], 0.f) : acc2[t][1];
        }
        if (EMIT_F32) {
            float4* op = (float4*)(out_f32 + (size_t)node * F + j0);
            #pragma unroll
            for (int t = 0; t < 4; ++t)
                op[t] = make_float4(r[4 * t], r[4 * t + 1],
                                    r[4 * t + 2], r[4 * t + 3]);
        } else {
            // h tables: fp16 (self path of layer 2) + fp8 (gather table)
            uint4 q0, q1;
            #pragma unroll
            for (int t = 0; t < 8; ++t)
                (t < 4 ? (&q0.x)[t] : (&q1.x)[t - 4]) = pkh(r[2*t], r[2*t+1]);
            uint4* ob = (uint4*)(out_h16 + (size_t)node * F + j0);
            ob[0] = q0; ob[1] = q1;

            uint4 p;
            #pragma unroll
            for (int t = 0; t < 4; ++t)
                (&p.x)[t] = fp8_pack4(r[4*t], r[4*t+1], r[4*t+2], r[4*t+3]);
            *(uint4*)(out_fp8 + (size_t)node * F + j0) = p;
        }
    }
}

// ---------------- fallback (round-3, all-fp32, fused) ----------------
template<bool RELU>
__global__ __launch_bounds__(256, 4)
void sage_layer_f32(const float* __restrict__ feat,
                    const float* __restrict__ W,
                    const float* __restrict__ bias,
                    const int*   __restrict__ src,
                    float*       __restrict__ out)
{
    __shared__ float buf[2 * F][STR];
    const int tid   = threadIdx.x;
    const int lane  = tid & 63;
    const int wave  = __builtin_amdgcn_readfirstlane(tid >> 6);
    const int node0 = blockIdx.x * NPB;

    #pragma unroll 2
    for (int m = 0; m < NPB / 4; ++m) {
        const int n    = wave * (NPB / 4) + m;
        const int node = node0 + n;
        if (node < NN) {
            buf[lane][n] = feat[node * F + lane];
            const int* sp = src + node * DEG;
            float s = 0.f;
            #pragma unroll
            for (int e = 0; e < DEG; ++e) s += feat[sp[e] * F + lane];
            buf[F + lane][n] = s * (1.0f / DEG);
        }
    }
    __syncthreads();

    const int j0 = wave * JPW;
    float acc[JPW];
    #pragma unroll
    for (int j = 0; j < JPW; ++j) acc[j] = bias[j0 + j];
    #pragma unroll 4
    for (int k = 0; k < 2 * F; ++k) {
        const float v = buf[k][lane];
        const float* Wr = W + k * F + j0;
        #pragma unroll
        for (int j = 0; j < JPW; ++j) acc[j] = fmaf(v, Wr[j], acc[j]);
    }
    const int node = node0 + lane;
    if (node < NN) {
        float4* op = (float4*)(out + node * F + j0);
        #pragma unroll
        for (int t = 0; t < 4; ++t) {
            float4 r = make_float4(acc[4 * t], acc[4 * t + 1],
                                   acc[4 * t + 2], acc[4 * t + 3]);
            if (RELU) {
                r.x = fmaxf(r.x, 0.f); r.y = fmaxf(r.y, 0.f);
                r.z = fmaxf(r.z, 0.f); r.w = fmaxf(r.w, 0.f);
            }
            op[t] = r;
        }
    }
}

extern "C" void kernel_launch(void* const* d_in, const int* in_sizes, int n_in,
                              void* d_out, int out_size, void* d_ws, size_t ws_size,
                              hipStream_t stream) {
    const float* x   = (const float*)d_in[0];
    const float* W1  = (const float*)d_in[1];
    const float* b1  = (const float*)d_in[2];
    const float* W2  = (const float*)d_in[3];
    const float* b2  = (const float*)d_in[4];
    const int*   src = (const int*)d_in[5];

    float* out = (float*)d_out;
    const int blocks = (NN + NPB - 1) / NPB;   // 1563

    const size_t hFP8 = (size_t)NN * F;                   //  6.4 MB
    const size_t hF16 = (size_t)NN * F * sizeof(ushort);  // 12.8 MB

    if (ws_size >= 2 * hFP8 + hF16) {
        unsigned char* x_fp8 = (unsigned char*)d_ws;
        ushort*        h_16  = (ushort*)((char*)d_ws + hFP8);
        unsigned char* h_fp8 = (unsigned char*)d_ws + hFP8 + hF16;

        const int n4 = NN * F / 4;
        cvt_f32_fp8<<<(n4 + 255) / 256, 256, 0, stream>>>(x, (unsigned*)x_fp8, n4);
        sage_fused<true,  true,  false><<<blocks, 256, 0, stream>>>(
            x, nullptr, x_fp8, W1, b1, src, nullptr, h_16, h_fp8);
        sage_fused<false, false, true ><<<blocks, 256, 0, stream>>>(
            nullptr, h_16, h_fp8, W2, b2, src, out, nullptr, nullptr);
    } else {
        float* h = (float*)d_ws;
        sage_layer_f32<true ><<<blocks, 256, 0, stream>>>(x, W1, b1, src, h);
        sage_layer_f32<false><<<blocks, 256, 0, stream>>>(h, W2, b2, src, out);
    }
}